// Round 3
// baseline (552.045 us; speedup 1.0000x reference)
//
#include <hip/hip_runtime.h>
#include <hip/hip_bf16.h>
#include <stdint.h>

#define N_ROWS 200000
#define C_DIM  128
#define TAPS   27
#define EPS    1e-5f

typedef __attribute__((ext_vector_type(8)))  short  short8;
typedef __attribute__((ext_vector_type(16))) float  floatx16;

__device__ __forceinline__ unsigned int f2bf(float f) {
  union { float f; unsigned int u; } v; v.f = f;
  unsigned int r = v.u + 0x7FFFu + ((v.u >> 16) & 1u);   // RNE, inputs finite
  return r >> 16;
}

__device__ __forceinline__ void glds16(const unsigned short* g, unsigned short* l) {
  __builtin_amdgcn_global_load_lds(
      (const __attribute__((address_space(1))) unsigned int*)g,
      (__attribute__((address_space(3))) unsigned int*)l, 16, 0, 0);
}

// ---------------- feats fp32 -> bf16 ----------------
__global__ __launch_bounds__(256) void k_cast(const float* __restrict__ in,
                                              unsigned short* __restrict__ out, int n8) {
  int i = blockIdx.x * 256 + threadIdx.x;
  if (i >= n8) return;
  const float4* p = (const float4*)in + (size_t)i * 2;
  float4 a = p[0], b = p[1];
  uint4 v;
  v.x = f2bf(a.x) | (f2bf(a.y) << 16);
  v.y = f2bf(a.z) | (f2bf(a.w) << 16);
  v.z = f2bf(b.x) | (f2bf(b.y) << 16);
  v.w = f2bf(b.z) | (f2bf(b.w) << 16);
  *(uint4*)(out + (size_t)i * 8) = v;
}

// ---- fold Linear into conv weights; emit MFMA B-fragment layout ----
// wfrag[k][nt(4)][s(8)][lane(64)][j(8)] (bf16):
//   B frag of mfma_f32_32x32x16_bf16: lane holds B[kk=(l>>5)*8+j][n=l&31]
//   kk_global = s*16 + (l>>5)*8 + j ; co = nt*32 + (l&31)
// Both streams (lin_w row, conv_w rows) are contiguous per thread -> float4.
__global__ __launch_bounds__(256) void k_fold(const float* __restrict__ conv_w,
                                              const float* __restrict__ lin_w,
                                              const float* __restrict__ conv_b,
                                              const float* __restrict__ lin_b,
                                              unsigned short* __restrict__ wfrag,
                                              float* __restrict__ biasf) {
  int id = blockIdx.x * 256 + threadIdx.x;
  const int NW = TAPS * 4 * 8 * 64;  // 55296
  if (id < NW) {
    int l  = id & 63;
    int s  = (id >> 6) & 7;
    int nt = (id >> 9) & 3;
    int k  = id >> 11;
    int ci0 = s * 16 + (l >> 5) * 8;
    int co  = nt * 32 + (l & 31);
    const float4* lw4 = (const float4*)(lin_w + (size_t)co * 128);
    const float4* cw4 = (const float4*)(conv_w + ((size_t)(k * 128 + ci0)) * 128);
    float acc[8] = {0, 0, 0, 0, 0, 0, 0, 0};
    for (int t4 = 0; t4 < 32; ++t4) {
      float4 lv = lw4[t4];
#pragma unroll
      for (int j = 0; j < 8; ++j) {
        float4 cv = cw4[j * 32 + t4];
        acc[j] += cv.x * lv.x + cv.y * lv.y + cv.z * lv.z + cv.w * lv.w;
      }
    }
    uint4 v;
    v.x = f2bf(acc[0]) | (f2bf(acc[1]) << 16);
    v.y = f2bf(acc[2]) | (f2bf(acc[3]) << 16);
    v.z = f2bf(acc[4]) | (f2bf(acc[5]) << 16);
    v.w = f2bf(acc[6]) | (f2bf(acc[7]) << 16);
    *(uint4*)(wfrag + (size_t)id * 8) = v;
  } else if (id < NW + 128) {
    int co = id - NW;
    const float* lw = lin_w + (size_t)co * 128;
    float s = lin_b[co];
    for (int t = 0; t < 128; ++t) s += conv_b[t] * lw[t];
    biasf[co] = s;
  }
}

// ---------------- fused gather-GEMM + LayerNorm ----------------
// 256 thr = 4 waves; wave w owns rows [blk*256 + w*64, +64) as 2 row-frags
// of 32, ALL 128 cols (4 col-frags). A: global->register gather, prefetched
// in place one tap ahead (load a[s] for tap k+1 right after step s of tap k
// consumed it). B: LDS double-buffer via global_load_lds staged AFTER the
// per-tap barrier (one barrier/tap), waited with manual vmcnt(18) so the
// in-flight A prefetches are never drained. LayerNorm fully in-wave.
__global__ __launch_bounds__(256, 2) void k_main(const unsigned short* __restrict__ featsB,
                                                 const int* __restrict__ nidx,
                                                 const unsigned short* __restrict__ wfrag,
                                                 const float* __restrict__ biasf,
                                                 const float* __restrict__ lnw,
                                                 const float* __restrict__ lnb,
                                                 float* __restrict__ out) {
  __shared__ unsigned short ldsB[2][16384];  // 2 x 32 KB

  const int tid = threadIdx.x;
  const int l   = tid & 63;
  const int w   = tid >> 6;
  const int l31 = l & 31;
  const int lh  = l >> 5;
  const int row0w = blockIdx.x * 256 + w * 64;

  const int gr0 = row0w + l31;
  const int gr1 = gr0 + 32;
  const int gc0 = (gr0 < N_ROWS) ? gr0 : N_ROWS - 1;
  const int gc1 = (gr1 < N_ROWS) ? gr1 : N_ROWS - 1;
  const int* np0 = nidx + (size_t)gc0 * TAPS;
  const int* np1 = nidx + (size_t)gc1 * TAPS;

  floatx16 acc[2][4];
#pragma unroll
  for (int rf = 0; rf < 2; ++rf)
#pragma unroll
    for (int c = 0; c < 4; ++c) acc[rf][c] = (floatx16){0.f};

  // ---- prologue ----
  // 1) stage B(0) FIRST (so the tap-0 vmcnt(18) covers exactly these glds)
#pragma unroll
  for (int r = 0; r < 8; ++r)
    glds16(wfrag + (size_t)r * 2048 + tid * 8, &ldsB[0][r * 2048 + w * 512]);
  // 2) tap-0 neighbor ids, then A(0) into registers
  int nidA0 = np0[0];
  int nidA1 = np1[0];
  short8 a0[8], a1[8];
  {
    const unsigned short* p0 = featsB + (size_t)(unsigned)nidA0 * 128 + lh * 8;
    const unsigned short* p1 = featsB + (size_t)(unsigned)nidA1 * 128 + lh * 8;
#pragma unroll
    for (int s = 0; s < 8; ++s) { a0[s] = *(const short8*)(p0 + s * 16);
                                  a1[s] = *(const short8*)(p1 + s * 16); }
  }
  // 3) neighbor ids for tap 1 (consumed by tap-0's in-loop A prefetch)
  int nidN0 = np0[1];
  int nidN1 = np1[1];

  for (int k = 0; k < TAPS; ++k) {
    const int cur = k & 1;
    // B(k) glds (staged last tap) are the 8 oldest outstanding VMEM ops;
    // 18 newer (16 A loads + 2 nid) may stay in flight.
    __builtin_amdgcn_s_waitcnt(0x4F72);  // vmcnt(18) expcnt(7) lgkmcnt(15)
    __builtin_amdgcn_s_barrier();        // all waves past tap k-1 reads

    // stage B(k+1) into the buffer freed by tap k-1 (safe: barrier above)
    const int kc1 = (k + 1 < TAPS) ? k + 1 : TAPS - 1;
    {
      const unsigned short* src = wfrag + (size_t)kc1 * 16384 + tid * 8;
      unsigned short* dst = &ldsB[cur ^ 1][w * 512];
#pragma unroll
      for (int r = 0; r < 8; ++r) glds16(src + r * 2048, dst + r * 2048);
    }

    // next-tap A base pointers (nidN loaded during tap k-1)
    const unsigned short* q0 = featsB + (size_t)(unsigned)nidN0 * 128 + lh * 8;
    const unsigned short* q1 = featsB + (size_t)(unsigned)nidN1 * 128 + lh * 8;

    const unsigned short* bb = &ldsB[cur][l * 8];
#pragma unroll
    for (int s = 0; s < 8; ++s) {
      short8 b0 = *(const short8*)(bb + (0 * 8 + s) * 512);
      short8 b1 = *(const short8*)(bb + (1 * 8 + s) * 512);
      short8 b2 = *(const short8*)(bb + (2 * 8 + s) * 512);
      short8 b3 = *(const short8*)(bb + (3 * 8 + s) * 512);
      acc[0][0] = __builtin_amdgcn_mfma_f32_32x32x16_bf16(a0[s], b0, acc[0][0], 0, 0, 0);
      acc[0][1] = __builtin_amdgcn_mfma_f32_32x32x16_bf16(a0[s], b1, acc[0][1], 0, 0, 0);
      acc[0][2] = __builtin_amdgcn_mfma_f32_32x32x16_bf16(a0[s], b2, acc[0][2], 0, 0, 0);
      acc[0][3] = __builtin_amdgcn_mfma_f32_32x32x16_bf16(a0[s], b3, acc[0][3], 0, 0, 0);
      acc[1][0] = __builtin_amdgcn_mfma_f32_32x32x16_bf16(a1[s], b0, acc[1][0], 0, 0, 0);
      acc[1][1] = __builtin_amdgcn_mfma_f32_32x32x16_bf16(a1[s], b1, acc[1][1], 0, 0, 0);
      acc[1][2] = __builtin_amdgcn_mfma_f32_32x32x16_bf16(a1[s], b2, acc[1][2], 0, 0, 0);
      acc[1][3] = __builtin_amdgcn_mfma_f32_32x32x16_bf16(a1[s], b3, acc[1][3], 0, 0, 0);
      // in-place prefetch of A(k+1) chunk s (full-tap slack until reuse)
      a0[s] = *(const short8*)(q0 + s * 16);
      a1[s] = *(const short8*)(q1 + s * 16);
    }
    // neighbor ids for tap k+2 (consumed by tap k+1's prefetch)
    const int kc2 = (k + 2 < TAPS) ? k + 2 : TAPS - 1;
    nidN0 = np0[kc2];
    nidN1 = np1[kc2];
  }

  // ---- epilogue: bias + in-wave LayerNorm + store ----
  float bb0 = biasf[l31], bb1 = biasf[32 + l31], bb2 = biasf[64 + l31], bb3 = biasf[96 + l31];
  float g0 = lnw[l31],    g1 = lnw[32 + l31],    g2 = lnw[64 + l31],    g3 = lnw[96 + l31];
  float c0 = lnb[l31],    c1 = lnb[32 + l31],    c2 = lnb[64 + l31],    c3 = lnb[96 + l31];

#pragma unroll
  for (int rf = 0; rf < 2; ++rf) {
#pragma unroll
    for (int r = 0; r < 16; ++r) {
      float x0 = acc[rf][0][r] + bb0, x1 = acc[rf][1][r] + bb1;
      float x2 = acc[rf][2][r] + bb2, x3 = acc[rf][3][r] + bb3;
      float s = x0 + x1 + x2 + x3;
      float q = x0 * x0 + x1 * x1 + x2 * x2 + x3 * x3;
#pragma unroll
      for (int off = 16; off >= 1; off >>= 1) {   // reduce within 32-lane half
        s += __shfl_xor(s, off, 64);
        q += __shfl_xor(q, off, 64);
      }
      float mu  = s * (1.0f / 128.0f);
      float var = q * (1.0f / 128.0f) - mu * mu;
      float rs  = rsqrtf(var + EPS);
      int row   = rf * 32 + (r & 3) + 8 * (r >> 2) + 4 * lh;  // 32x32 C/D row map
      int grow  = row0w + row;
      if (grow < N_ROWS) {
        float* o = out + (size_t)grow * 128;
        o[l31]      = (x0 - mu) * rs * g0 + c0;
        o[32 + l31] = (x1 - mu) * rs * g1 + c1;
        o[64 + l31] = (x2 - mu) * rs * g2 + c2;
        o[96 + l31] = (x3 - mu) * rs * g3 + c3;
      }
    }
  }
}

extern "C" void kernel_launch(void* const* d_in, const int* in_sizes, int n_in,
                              void* d_out, int out_size, void* d_ws, size_t ws_size,
                              hipStream_t stream) {
  const float* feats  = (const float*)d_in[0];
  const int*   nidx   = (const int*)d_in[1];
  const float* conv_w = (const float*)d_in[2];
  const float* conv_b = (const float*)d_in[3];
  const float* lin_w  = (const float*)d_in[4];
  const float* lin_b  = (const float*)d_in[5];
  const float* ln_w   = (const float*)d_in[6];
  const float* ln_b   = (const float*)d_in[7];
  float* out = (float*)d_out;

  unsigned short* featsB = (unsigned short*)d_ws;                       // 51,200,000 B
  unsigned short* wfrag  = (unsigned short*)((char*)d_ws + 51200000);   //    884,736 B
  float*          biasf  = (float*)((char*)d_ws + 51200000 + 884736);   //        512 B

  int n8 = N_ROWS * C_DIM / 8;  // 3,200,000
  k_cast<<<(n8 + 255) / 256, 256, 0, stream>>>(feats, featsB, n8);
  k_fold<<<(TAPS * 2048 + 128 + 255) / 256, 256, 0, stream>>>(conv_w, lin_w, conv_b, lin_b,
                                                              wfrag, biasf);
  k_main<<<(N_ROWS + 255) / 256, 256, 0, stream>>>(featsB, nidx, wfrag, biasf, ln_w, ln_b, out);
}